// Round 9
// baseline (223.324 us; speedup 1.0000x reference)
//
#include <hip/hip_runtime.h>

#define T_SEQ 8192
#define E_DIM 1024
#define QS 36              // padded qkv row: [k 0..10][pad][q 12..22][pad][v 24..34][pad]
#define QNEC 16            // E-chunks in qkv projection
#define QKC 64             // cols per qkv chunk
#define QX4 16             // QKC/4 float4-cols
#define QXST 17            // padded f4 stride (68 words = 4 mod 32 -> conflict-free b128)
#define QRB 256            // qkv rows per block (4/thread)
#define AJC 64             // attn j-chunk rows
#define ARB 1024           // attn rows per block (4/thread)
#define ANIB (T_SEQ / ARB) // 8
#define KVW 32             // LDS kv row stride (floats): [k0..10,p][v0..10,p][8 unused]
#define TR 16              // pass2 rows per block
#define LOG2E 1.4426950408889634f

__device__ __forceinline__ float2 pkfma(float2 a, float2 b, float2 c) {
    return make_float2(fmaf(a.x, b.x, c.x), fmaf(a.y, b.y, c.y));
}
__device__ __forceinline__ float2 f2(float x, float y) { return make_float2(x, y); }

// ws floats (overlaid): qkvF[T][QS] 1.18MB | wfp[E][12] 48KB |
//   region R: partQ[QNEC][T][QS] 18.9MB overlaid by part[64][T][12] 25.2MB
//   (partQ dead after reduceQ; stream-ordered). ~26.4MB total (proven safe).

// ---------------------------------------------------------------------------
// K0: pad Wf [E][11] -> [E][12] for coalesced float4 loads in pass2
// ---------------------------------------------------------------------------
__global__ __launch_bounds__(256) void prep_wf(const float* __restrict__ Wf,
                                               float* __restrict__ Wfp) {
    int id = blockIdx.x * 256 + threadIdx.x;
    if (id >= E_DIM * 12) return;
    int e = id / 12, d = id % 12;
    Wfp[id] = (d < 11) ? Wf[(size_t)e * 11 + d] : 0.f;
}

// ---------------------------------------------------------------------------
// K1: qkv projection, R=4 rows/thread (R8 lesson: LDS-pipe-bound at R=1 —
// weight broadcasts amortize over nothing; 4 rows -> 13 LDS reads per 72
// pkfma = VALU-bound). Block: 256 rows x 64 cols; wave wg owns 9 outputs;
// thread owns rows lane+{0,64,128,192}. 512 blocks (32 row x 16 E-chunks).
// LDS: xT 69.6KB + wT 9.2KB -> 2 blocks/CU.
// ---------------------------------------------------------------------------
__global__ __launch_bounds__(256, 2) void qkv_proj(
    const float* __restrict__ xe,
    const float* __restrict__ Wk, const float* __restrict__ bk,
    const float* __restrict__ Wq, const float* __restrict__ bq,
    const float* __restrict__ Wv, const float* __restrict__ bv,
    float* __restrict__ partQ) {
    const int row0 = blockIdx.x * QRB;
    const int ec = blockIdx.y;
    const int lane = threadIdx.x & 63;
    const int wg = threadIdx.x >> 6;
    const int cb = ec * QKC;

    __shared__ float4 xT[QRB * QXST];     // 69.6 KB
    __shared__ float4 wT[36 * QX4];       // 9.2 KB

    // stage xe tile: 4096 f4, 16/thread, 16 threads per 256B row (coalesced)
#pragma unroll
    for (int t = 0; t < 16; ++t) {
        int idx = threadIdx.x + t * 256;
        int r = idx >> 4, c4 = idx & 15;
        xT[r * QXST + c4] =
            *(const float4*)(xe + (size_t)(row0 + r) * E_DIM + cb + c4 * 4);
    }
    // stage W tile: 36 rows x 16 f4 (rows 33..35 zero)
    for (int idx = threadIdx.x; idx < 36 * QX4; idx += 256) {
        int r = idx >> 4, c4 = idx & 15;
        float4 v = make_float4(0.f, 0.f, 0.f, 0.f);
        if (r < 33) {
            const float* base = (r < 11) ? (Wk + (size_t)r * E_DIM)
                              : (r < 22) ? (Wq + (size_t)(r - 11) * E_DIM)
                                         : (Wv + (size_t)(r - 22) * E_DIM);
            v = *(const float4*)(base + cb + c4 * 4);
        }
        wT[idx] = v;
    }
    __syncthreads();

    float2 acc[4][9];
#pragma unroll
    for (int u = 0; u < 4; ++u)
#pragma unroll
        for (int k = 0; k < 9; ++k) acc[u][k] = f2(0.f, 0.f);

    const float4* xr = xT + lane * QXST;
    const float4* wr = wT + wg * 9 * QX4;
#pragma unroll 4
    for (int c4 = 0; c4 < QX4; ++c4) {
        float4 xv0 = xr[c4];
        float4 xv1 = xr[64 * QXST + c4];
        float4 xv2 = xr[128 * QXST + c4];
        float4 xv3 = xr[192 * QXST + c4];
#pragma unroll
        for (int k = 0; k < 9; ++k) {
            float4 wv = wr[k * QX4 + c4];          // broadcast
            float2 wlo = f2(wv.x, wv.y), whi = f2(wv.z, wv.w);
            acc[0][k] = pkfma(f2(xv0.x, xv0.y), wlo, acc[0][k]);
            acc[0][k] = pkfma(f2(xv0.z, xv0.w), whi, acc[0][k]);
            acc[1][k] = pkfma(f2(xv1.x, xv1.y), wlo, acc[1][k]);
            acc[1][k] = pkfma(f2(xv1.z, xv1.w), whi, acc[1][k]);
            acc[2][k] = pkfma(f2(xv2.x, xv2.y), wlo, acc[2][k]);
            acc[2][k] = pkfma(f2(xv2.z, xv2.w), whi, acc[2][k]);
            acc[3][k] = pkfma(f2(xv3.x, xv3.y), wlo, acc[3][k]);
            acc[3][k] = pkfma(f2(xv3.z, xv3.w), whi, acc[3][k]);
        }
    }

    float* dst = partQ + ((size_t)ec * T_SEQ + row0 + lane) * QS;
#pragma unroll
    for (int k = 0; k < 9; ++k) {
        int o = wg * 9 + k;
        bool live = (o < 33);
        int c = (o < 11) ? o : (o < 22) ? o + 1 : (o < 33) ? o + 2
              : (o == 33) ? 11 : (o == 34) ? 23 : 35;
        float b = 0.f;
        if (ec == 0 && live)
            b = (o < 11) ? bk[o] : (o < 22) ? bq[o - 11] : bv[o - 22];
#pragma unroll
        for (int u = 0; u < 4; ++u)
            dst[(size_t)u * 64 * QS + c] = live ? (acc[u][k].x + acc[u][k].y + b) : 0.f;
    }
}

// ---------------------------------------------------------------------------
// K2: reduce QNEC qkv partial chunks into dense qkvF.
// ---------------------------------------------------------------------------
__global__ __launch_bounds__(256) void reduceQ(const float* __restrict__ partQ,
                                               float* __restrict__ qkvF) {
    const size_t idx = (size_t)blockIdx.x * 256 + threadIdx.x;
    const float4* p = (const float4*)partQ;
    const size_t cs = (size_t)T_SEQ * (QS / 4);
    float4 s = make_float4(0.f, 0.f, 0.f, 0.f);
#pragma unroll
    for (int c = 0; c < QNEC; ++c) {
        float4 a = p[idx + (size_t)c * cs];
        s.x += a.x; s.y += a.y; s.z += a.z; s.w += a.w;
    }
    ((float4*)qkvF)[idx] = s;
}

// ---------------------------------------------------------------------------
// K3: causal attention, R=4 rows/thread. Block covers ARB=1024 rows
// (thread -> rows rbase..rbase+3) and a balanced chunk pair (s, C-1-s) where
// C = 16*(ib+1): exactly 128 j-iters per block. 288 blocks, 64 part slots.
// Per j-iter: 6 broadcast b128 vs ~64 VALU inst -> VALU-bound (R8 lesson).
// ---------------------------------------------------------------------------
__device__ __forceinline__ void stage_kv(const float* __restrict__ qkvF,
                                         float* kv, int j0) {
    // 64 rows x 6 f4 (k at qkv cols 0..11, v at 24..35), kv stride 32 floats
    for (int idx = threadIdx.x; idx < AJC * 8; idx += 256) {
        int row = idx >> 3, f = idx & 7;
        if (f < 6) {
            int srcOff = f * 4 + (f >= 3 ? 12 : 0);
            float4 v = *(const float4*)(qkvF + (size_t)(j0 + row) * QS + srcOff);
            *(float4*)(kv + row * KVW + f * 4) = v;
        }
    }
}

__global__ __launch_bounds__(256, 2) void attn(const float* __restrict__ qkvF,
                                               float* __restrict__ part) {
    const int b = blockIdx.x;
    int ib = 0;
    while (4 * (ib + 1) * (ib + 2) <= b) ++ib;    // prefix(ib) = 4*ib*(ib+1)
    const int s = b - 4 * ib * (ib + 1);          // s in [0, 8*(ib+1))
    const int C = 16 * (ib + 1);                  // chunks for this row-block

    const int rbase = ib * ARB + threadIdx.x * 4;

    // load + pre-scale q for 4 rows, packed as 6 f2 each (last pairs with 0)
    float2 q[4][6];
#pragma unroll
    for (int u = 0; u < 4; ++u) {
        const float* qp = qkvF + (size_t)(rbase + u) * QS + 12;
#pragma unroll
        for (int d = 0; d < 5; ++d)
            q[u][d] = f2(qp[2 * d] * LOG2E, qp[2 * d + 1] * LOG2E);
        q[u][5] = f2(qp[10] * LOG2E, 0.f);
    }

    float2 acc[4][6];
#pragma unroll
    for (int u = 0; u < 4; ++u)
#pragma unroll
        for (int d = 0; d < 6; ++d) acc[u][d] = f2(0.f, 0.f);

    __shared__ float kv[AJC * KVW];

#pragma unroll
    for (int pass = 0; pass < 2; ++pass) {
        const int jc = pass ? (C - 1 - s) : s;
        const int j0 = jc * AJC;
        if (pass) __syncthreads();                // WAR on kv
        stage_kv(qkvF, kv, j0);
        __syncthreads();

        for (int jj = 0; jj < AJC; ++jj) {
            const float* kp = kv + jj * KVW;
            const float4 kA = *(const float4*)(kp);
            const float4 kB = *(const float4*)(kp + 4);
            const float4 kC = *(const float4*)(kp + 8);   // .w = 0 (pad col 11)
            const float4 vA = *(const float4*)(kp + 12);
            const float4 vB = *(const float4*)(kp + 16);
            const float4 vC = *(const float4*)(kp + 20);  // .w = 0 (pad col 35)
            const float2 k01 = f2(kA.x, kA.y), k23 = f2(kA.z, kA.w);
            const float2 k45 = f2(kB.x, kB.y), k67 = f2(kB.z, kB.w);
            const float2 k89 = f2(kC.x, kC.y), kXp = f2(kC.z, kC.w);
            const int j = j0 + jj;

            float p[4];
#pragma unroll
            for (int u = 0; u < 4; ++u) {
                float2 sv = pkfma(q[u][0], k01,
                            pkfma(q[u][1], k23,
                            pkfma(q[u][2], k45,
                            pkfma(q[u][3], k67,
                            pkfma(q[u][4], k89,
                            pkfma(q[u][5], kXp, f2(0.f, 0.f)))))));
                float e = exp2f(sv.x + sv.y);
                p[u] = (j <= rbase + u) ? e : 0.f;
            }
#pragma unroll
            for (int u = 0; u < 4; ++u) {
                float2 p2 = f2(p[u], p[u]);
                acc[u][0] = pkfma(p2, f2(vA.x, vA.y), acc[u][0]);
                acc[u][1] = pkfma(p2, f2(vA.z, vA.w), acc[u][1]);
                acc[u][2] = pkfma(p2, f2(vB.x, vB.y), acc[u][2]);
                acc[u][3] = pkfma(p2, f2(vB.z, vB.w), acc[u][3]);
                acc[u][4] = pkfma(p2, f2(vC.x, vC.y), acc[u][4]);
                acc[u][5] = pkfma(p2, f2(vC.z, 1.f), acc[u][5]);  // o10, l
            }
        }
    }

#pragma unroll
    for (int u = 0; u < 4; ++u) {
        float* dst = part + ((size_t)s * T_SEQ + rbase + u) * 12;
        float4 t;
        t.x = acc[u][0].x; t.y = acc[u][0].y; t.z = acc[u][1].x; t.w = acc[u][1].y;
        *(float4*)(dst + 0) = t;
        t.x = acc[u][2].x; t.y = acc[u][2].y; t.z = acc[u][3].x; t.w = acc[u][3].y;
        *(float4*)(dst + 4) = t;
        t.x = acc[u][4].x; t.y = acc[u][4].y; t.z = acc[u][5].x; t.w = acc[u][5].y;
        *(float4*)(dst + 8) = t;
    }
}

// ---------------------------------------------------------------------------
// K4: fused partial-reduce + normalize + output GEMM + bias.
// Slot count for rows in attn row-block ib: 8*(ib+1), ib = t0/1024.
// ---------------------------------------------------------------------------
__global__ __launch_bounds__(256) void pass2(const float* __restrict__ part,
                                             const float* __restrict__ Wfp,
                                             const float* __restrict__ bf,
                                             float* __restrict__ out) {
    const int t0 = blockIdx.x * TR;
    __shared__ float res[TR][12];
    const int cnt = 8 * (t0 / ARB) + 8;           // uniform per block, <= 64
    if (threadIdx.x < TR * 12) {
        const float* p = part + (size_t)t0 * 12 + threadIdx.x;
        const size_t S = (size_t)T_SEQ * 12;
        float v[4];
#pragma unroll
        for (int u = 0; u < 4; ++u) v[u] = 0.f;
        for (int c = 0; c < cnt; c += 4) {
#pragma unroll
            for (int u = 0; u < 4; ++u) v[u] += p[(size_t)(c + u) * S];
        }
        float sum = (v[0] + v[1]) + (v[2] + v[3]);
        const int d = threadIdx.x % 12;
        res[threadIdx.x / 12][d] = (d == 11) ? (1.f / sum) : sum;
    }
    __syncthreads();

    const int e0 = threadIdx.x * 4;
    float4 wf[4][3];
#pragma unroll
    for (int ee = 0; ee < 4; ++ee) {
        const float4* wp = (const float4*)(Wfp + (size_t)(e0 + ee) * 12);
        wf[ee][0] = wp[0]; wf[ee][1] = wp[1]; wf[ee][2] = wp[2];
    }
    const float4 bv = *(const float4*)(bf + e0);

    for (int r = 0; r < TR; ++r) {
        float rr[12];
#pragma unroll
        for (int d = 0; d < 12; ++d) rr[d] = res[r][d];
        float2 a0 = f2(0.f, 0.f), a1 = a0, a2 = a0, a3 = a0;
#pragma unroll
        for (int d = 0; d < 10; d += 2) {
            float2 rv = f2(rr[d], rr[d + 1]);
            a0 = pkfma(rv, f2(((const float*)&wf[0][0])[d], ((const float*)&wf[0][0])[d + 1]), a0);
            a1 = pkfma(rv, f2(((const float*)&wf[1][0])[d], ((const float*)&wf[1][0])[d + 1]), a1);
            a2 = pkfma(rv, f2(((const float*)&wf[2][0])[d], ((const float*)&wf[2][0])[d + 1]), a2);
            a3 = pkfma(rv, f2(((const float*)&wf[3][0])[d], ((const float*)&wf[3][0])[d + 1]), a3);
        }
        const float rl = rr[11];
        float4 ov;
        ov.x = (a0.x + a0.y + rr[10] * wf[0][2].z) * rl + bv.x;
        ov.y = (a1.x + a1.y + rr[10] * wf[1][2].z) * rl + bv.y;
        ov.z = (a2.x + a2.y + rr[10] * wf[2][2].z) * rl + bv.z;
        ov.w = (a3.x + a3.y + rr[10] * wf[3][2].z) * rl + bv.w;
        *(float4*)(out + (size_t)(t0 + r) * E_DIM + e0) = ov;
    }
}

// ---------------------------------------------------------------------------
extern "C" void kernel_launch(void* const* d_in, const int* in_sizes, int n_in,
                              void* d_out, int out_size, void* d_ws, size_t ws_size,
                              hipStream_t stream) {
    const float* xe = (const float*)d_in[1];
    const float* Wk = (const float*)d_in[2];
    const float* bk = (const float*)d_in[3];
    const float* Wq = (const float*)d_in[4];
    const float* bq = (const float*)d_in[5];
    const float* Wv = (const float*)d_in[6];
    const float* bv = (const float*)d_in[7];
    const float* Wf = (const float*)d_in[8];
    const float* bf = (const float*)d_in[9];
    float* out = (float*)d_out;

    float* qkvF  = (float*)d_ws;                              // [T][QS]
    float* wfp   = qkvF + (size_t)T_SEQ * QS;                 // [E][12]
    float* partQ = wfp + (size_t)E_DIM * 12;                  // [QNEC][T][QS]
    float* part  = partQ;                                     // overlay: [64][T][12]

    prep_wf<<<(E_DIM * 12 + 255) / 256, 256, 0, stream>>>(Wf, wfp);
    qkv_proj<<<dim3(T_SEQ / QRB, QNEC), 256, 0, stream>>>(xe, Wk, bk, Wq, bq, Wv, bv, partQ);
    reduceQ<<<(T_SEQ * (QS / 4)) / 256, 256, 0, stream>>>(partQ, qkvF);
    attn<<<4 * ANIB * (ANIB + 1), 256, 0, stream>>>(qkvF, part);   // 288 blocks
    pass2<<<T_SEQ / TR, 256, 0, stream>>>(part, wfp, bf, out);
}

// Round 10
// 192.119 us; speedup vs baseline: 1.1624x; 1.1624x over previous
//
#include <hip/hip_runtime.h>

#define T_SEQ 8192
#define E_DIM 1024
#define QS 36              // padded qkv row: [k 0..10][pad][q 12..22][pad][v 24..34][pad]
#define QNEC 16            // E-chunks in qkv projection
#define QKC 64             // cols per qkv chunk
#define QX4 16             // QKC/4 float4-cols
#define QXST 17            // f4 stride: 68 words = 4 mod 32 -> clean 4-word bank rotation
#define QRB 128            // qkv rows per block (2/thread)
#define AJC 64             // attn j-chunk rows
#define ARB 128            // attn rows per block (2/thread, 64-thread block)
#define KVW 24             // LDS kv row: [k0..10,pad][v0..10,pad]
#define TR 16              // pass2 rows per block
#define LOG2E 1.4426950408889634f

__device__ __forceinline__ float2 pkfma(float2 a, float2 b, float2 c) {
    return make_float2(fmaf(a.x, b.x, c.x), fmaf(a.y, b.y, c.y));
}
__device__ __forceinline__ float2 f2(float x, float y) { return make_float2(x, y); }

// ws floats (overlaid): qkvF[T][QS] 1.18MB | wfp[E][12] 48KB |
//   region R: partQ[QNEC][T][QS] 18.9MB overlaid by part[64][T][12] 25.2MB
//   (partQ dead after reduceQ; stream-ordered). ~26.4MB total (proven safe).

// ---------------------------------------------------------------------------
// K0: pad Wf [E][11] -> [E][12] for coalesced float4 loads in pass2
// ---------------------------------------------------------------------------
__global__ __launch_bounds__(256) void prep_wf(const float* __restrict__ Wf,
                                               float* __restrict__ Wfp) {
    int id = blockIdx.x * 256 + threadIdx.x;
    if (id >= E_DIM * 12) return;
    int e = id / 12, d = id % 12;
    Wfp[id] = (d < 11) ? Wf[(size_t)e * 11 + d] : 0.f;
}

// ---------------------------------------------------------------------------
// K1: qkv projection. Block 256 thr = 128 rows x 64 cols, R=2 rows/thread.
// LDS 44KB (xT 34.8 + wT 9.2) -> 3 blocks/CU resident; grid 1024 blocks.
// Per c4-iter: 2 per-lane b128 x-reads + 9 broadcast b128 w-reads feeding
// 36 pkfma -> VALU-bound with 12 waves/CU to hide LDS latency.
// ---------------------------------------------------------------------------
__global__ __launch_bounds__(256) void qkv_proj(
    const float* __restrict__ xe,
    const float* __restrict__ Wk, const float* __restrict__ bk,
    const float* __restrict__ Wq, const float* __restrict__ bq,
    const float* __restrict__ Wv, const float* __restrict__ bv,
    float* __restrict__ partQ) {
    const int row0 = blockIdx.x * QRB;
    const int ec = blockIdx.y;
    const int lane = threadIdx.x & 63;
    const int wg = threadIdx.x >> 6;
    const int cb = ec * QKC;

    __shared__ float4 xT[QRB * QXST];     // 34.8 KB
    __shared__ float4 wT[36 * QX4];       // 9.2 KB

    // stage xe tile: 2048 f4, 8/thread, 16 threads per 256B row (coalesced)
#pragma unroll
    for (int t = 0; t < 8; ++t) {
        int idx = threadIdx.x + t * 256;
        int r = idx >> 4, c4 = idx & 15;
        xT[r * QXST + c4] =
            *(const float4*)(xe + (size_t)(row0 + r) * E_DIM + cb + c4 * 4);
    }
    // stage W tile: 36 rows x 16 f4 (rows 33..35 zero)
    for (int idx = threadIdx.x; idx < 36 * QX4; idx += 256) {
        int r = idx >> 4, c4 = idx & 15;
        float4 v = make_float4(0.f, 0.f, 0.f, 0.f);
        if (r < 33) {
            const float* base = (r < 11) ? (Wk + (size_t)r * E_DIM)
                              : (r < 22) ? (Wq + (size_t)(r - 11) * E_DIM)
                                         : (Wv + (size_t)(r - 22) * E_DIM);
            v = *(const float4*)(base + cb + c4 * 4);
        }
        wT[idx] = v;
    }
    __syncthreads();

    float2 acc[2][9];
#pragma unroll
    for (int u = 0; u < 2; ++u)
#pragma unroll
        for (int k = 0; k < 9; ++k) acc[u][k] = f2(0.f, 0.f);

    const float4* xr = xT + lane * QXST;
    const float4* wr = wT + wg * 9 * QX4;
#pragma unroll 4
    for (int c4 = 0; c4 < QX4; ++c4) {
        float4 xv0 = xr[c4];
        float4 xv1 = xr[64 * QXST + c4];
#pragma unroll
        for (int k = 0; k < 9; ++k) {
            float4 wv = wr[k * QX4 + c4];          // broadcast
            float2 wlo = f2(wv.x, wv.y), whi = f2(wv.z, wv.w);
            acc[0][k] = pkfma(f2(xv0.x, xv0.y), wlo, acc[0][k]);
            acc[0][k] = pkfma(f2(xv0.z, xv0.w), whi, acc[0][k]);
            acc[1][k] = pkfma(f2(xv1.x, xv1.y), wlo, acc[1][k]);
            acc[1][k] = pkfma(f2(xv1.z, xv1.w), whi, acc[1][k]);
        }
    }

    float* dst = partQ + ((size_t)ec * T_SEQ + row0 + lane) * QS;
#pragma unroll
    for (int k = 0; k < 9; ++k) {
        int o = wg * 9 + k;
        bool live = (o < 33);
        int c = (o < 11) ? o : (o < 22) ? o + 1 : (o < 33) ? o + 2
              : (o == 33) ? 11 : (o == 34) ? 23 : 35;
        float b = 0.f;
        if (ec == 0 && live)
            b = (o < 11) ? bk[o] : (o < 22) ? bq[o - 11] : bv[o - 22];
#pragma unroll
        for (int u = 0; u < 2; ++u)
            dst[(size_t)u * 64 * QS + c] = live ? (acc[u][k].x + acc[u][k].y + b) : 0.f;
    }
}

// ---------------------------------------------------------------------------
// K2: reduce QNEC qkv partial chunks into dense qkvF.
// ---------------------------------------------------------------------------
__global__ __launch_bounds__(256) void reduceQ(const float* __restrict__ partQ,
                                               float* __restrict__ qkvF) {
    const size_t idx = (size_t)blockIdx.x * 256 + threadIdx.x;
    const float4* p = (const float4*)partQ;
    const size_t cs = (size_t)T_SEQ * (QS / 4);
    float4 s = make_float4(0.f, 0.f, 0.f, 0.f);
#pragma unroll
    for (int c = 0; c < QNEC; ++c) {
        float4 a = p[idx + (size_t)c * cs];
        s.x += a.x; s.y += a.y; s.z += a.z; s.w += a.w;
    }
    ((float4*)qkvF)[idx] = s;
}

// ---------------------------------------------------------------------------
// K3: causal attention, ONE-WAVE blocks (64 thr). Block b -> row-group rb
// (128 rows: rb*128 + lane*2, R=2) and balanced chunk pair (s, 2rb+1-s):
// exactly 128 j-iters/block, 2080 uniform blocks, 6KB LDS -> deep per-CU
// packing (no cross-wave barrier coupling). __expf (bare v_exp_f32), R8-style
// always-masked. Partials to part[s][row][12], no atomics.
// ---------------------------------------------------------------------------
__global__ __launch_bounds__(64) void attn(const float* __restrict__ qkvF,
                                           float* __restrict__ part) {
    const int b = blockIdx.x;
    int rb = 0;
    while ((rb + 1) * (rb + 2) / 2 <= b) ++rb;    // prefix(rb) = rb(rb+1)/2
    const int s = b - rb * (rb + 1) / 2;          // s in [0, rb]
    const int lane = threadIdx.x;
    const int r0 = rb * ARB + lane * 2;

    // q for 2 rows, packed as 6 f2 (pair 5 = (q10, 0))
    const float* qp0 = qkvF + (size_t)r0 * QS + 12;
    const float* qp1 = qp0 + QS;
    float2 qa[6], qb[6];
#pragma unroll
    for (int d = 0; d < 5; ++d) {
        qa[d] = f2(qp0[2 * d], qp0[2 * d + 1]);
        qb[d] = f2(qp1[2 * d], qp1[2 * d + 1]);
    }
    qa[5] = f2(qp0[10], 0.f);
    qb[5] = f2(qp1[10], 0.f);

    float2 oa[6], ob[6];
#pragma unroll
    for (int d = 0; d < 6; ++d) { oa[d] = f2(0.f, 0.f); ob[d] = f2(0.f, 0.f); }

    __shared__ float kv[AJC * KVW];               // 6 KB

#pragma unroll
    for (int pass = 0; pass < 2; ++pass) {
        const int jc = pass ? (2 * rb + 1 - s) : s;
        const int j0 = jc * AJC;
        if (pass) __syncthreads();                // WAR on kv (1-wave barrier)
        // stage 64 rows x 6 f4; 384 f4, 6 per lane
#pragma unroll
        for (int t = 0; t < 6; ++t) {
            int idx = lane + t * 64;
            int row = idx / 6, f = idx % 6;
            int srcOff = f * 4 + (f >= 3 ? 12 : 0);
            float4 v = *(const float4*)(qkvF + (size_t)(j0 + row) * QS + srcOff);
            *(float4*)(kv + row * KVW + f * 4) = v;
        }
        __syncthreads();

        for (int jj = 0; jj < AJC; ++jj) {
            const float* kp = kv + jj * KVW;
            const float4 kA = *(const float4*)(kp);
            const float4 kB = *(const float4*)(kp + 4);
            const float4 kC = *(const float4*)(kp + 8);   // .w = 0 (pad)
            const float4 vA = *(const float4*)(kp + 12);
            const float4 vB = *(const float4*)(kp + 16);
            const float4 vC = *(const float4*)(kp + 20);  // .w = 0 (pad)
            const float2 k01 = f2(kA.x, kA.y), k23 = f2(kA.z, kA.w);
            const float2 k45 = f2(kB.x, kB.y), k67 = f2(kB.z, kB.w);
            const float2 k89 = f2(kC.x, kC.y), kXp = f2(kC.z, kC.w);

            float2 sa = pkfma(qa[0], k01, pkfma(qa[1], k23, pkfma(qa[2], k45,
                        pkfma(qa[3], k67, pkfma(qa[4], k89,
                        pkfma(qa[5], kXp, f2(0.f, 0.f)))))));
            float2 sb = pkfma(qb[0], k01, pkfma(qb[1], k23, pkfma(qb[2], k45,
                        pkfma(qb[3], k67, pkfma(qb[4], k89,
                        pkfma(qb[5], kXp, f2(0.f, 0.f)))))));
            float pa = __expf(sa.x + sa.y);
            float pb = __expf(sb.x + sb.y);
            const int j = j0 + jj;
            pa = (j <= r0)     ? pa : 0.f;
            pb = (j <= r0 + 1) ? pb : 0.f;
            float2 pa2 = f2(pa, pa), pb2 = f2(pb, pb);
            oa[0] = pkfma(pa2, f2(vA.x, vA.y), oa[0]);
            oa[1] = pkfma(pa2, f2(vA.z, vA.w), oa[1]);
            oa[2] = pkfma(pa2, f2(vB.x, vB.y), oa[2]);
            oa[3] = pkfma(pa2, f2(vB.z, vB.w), oa[3]);
            oa[4] = pkfma(pa2, f2(vC.x, vC.y), oa[4]);
            oa[5] = pkfma(pa2, f2(vC.z, 1.f),  oa[5]);    // o10, l
            ob[0] = pkfma(pb2, f2(vA.x, vA.y), ob[0]);
            ob[1] = pkfma(pb2, f2(vA.z, vA.w), ob[1]);
            ob[2] = pkfma(pb2, f2(vB.x, vB.y), ob[2]);
            ob[3] = pkfma(pb2, f2(vB.z, vB.w), ob[3]);
            ob[4] = pkfma(pb2, f2(vC.x, vC.y), ob[4]);
            ob[5] = pkfma(pb2, f2(vC.z, 1.f),  ob[5]);
        }
    }

    float* d0 = part + ((size_t)s * T_SEQ + r0) * 12;
    float4 t;
    t.x = oa[0].x; t.y = oa[0].y; t.z = oa[1].x; t.w = oa[1].y; *(float4*)(d0 + 0) = t;
    t.x = oa[2].x; t.y = oa[2].y; t.z = oa[3].x; t.w = oa[3].y; *(float4*)(d0 + 4) = t;
    t.x = oa[4].x; t.y = oa[4].y; t.z = oa[5].x; t.w = oa[5].y; *(float4*)(d0 + 8) = t;
    float* d1 = d0 + 12;
    t.x = ob[0].x; t.y = ob[0].y; t.z = ob[1].x; t.w = ob[1].y; *(float4*)(d1 + 0) = t;
    t.x = ob[2].x; t.y = ob[2].y; t.z = ob[3].x; t.w = ob[3].y; *(float4*)(d1 + 4) = t;
    t.x = ob[4].x; t.y = ob[4].y; t.z = ob[5].x; t.w = ob[5].y; *(float4*)(d1 + 8) = t;
}

// ---------------------------------------------------------------------------
// K4: fused partial-reduce + normalize + output GEMM + bias.
// Slot count for row t: t/128 + 1 (<= 64), uniform per 16-row block.
// ---------------------------------------------------------------------------
__global__ __launch_bounds__(256) void pass2(const float* __restrict__ part,
                                             const float* __restrict__ Wfp,
                                             const float* __restrict__ bf,
                                             float* __restrict__ out) {
    const int t0 = blockIdx.x * TR;
    __shared__ float res[TR][12];
    const int cnt = t0 / ARB + 1;                 // uniform per block
    if (threadIdx.x < TR * 12) {
        const float* p = part + (size_t)t0 * 12 + threadIdx.x;
        const size_t S = (size_t)T_SEQ * 12;
        float v[4];
#pragma unroll
        for (int u = 0; u < 4; ++u) v[u] = 0.f;
        int c = 0;
        for (; c + 4 <= cnt; c += 4) {
#pragma unroll
            for (int u = 0; u < 4; ++u) v[u] += p[(size_t)(c + u) * S];
        }
        for (; c < cnt; ++c) v[0] += p[(size_t)c * S];
        float sum = (v[0] + v[1]) + (v[2] + v[3]);
        const int d = threadIdx.x % 12;
        res[threadIdx.x / 12][d] = (d == 11) ? (1.f / sum) : sum;
    }
    __syncthreads();

    const int e0 = threadIdx.x * 4;
    float4 wf[4][3];
#pragma unroll
    for (int ee = 0; ee < 4; ++ee) {
        const float4* wp = (const float4*)(Wfp + (size_t)(e0 + ee) * 12);
        wf[ee][0] = wp[0]; wf[ee][1] = wp[1]; wf[ee][2] = wp[2];
    }
    const float4 bv = *(const float4*)(bf + e0);

    for (int r = 0; r < TR; ++r) {
        float rr[12];
#pragma unroll
        for (int d = 0; d < 12; ++d) rr[d] = res[r][d];
        float2 a0 = f2(0.f, 0.f), a1 = a0, a2 = a0, a3 = a0;
#pragma unroll
        for (int d = 0; d < 10; d += 2) {
            float2 rv = f2(rr[d], rr[d + 1]);
            a0 = pkfma(rv, f2(((const float*)&wf[0][0])[d], ((const float*)&wf[0][0])[d + 1]), a0);
            a1 = pkfma(rv, f2(((const float*)&wf[1][0])[d], ((const float*)&wf[1][0])[d + 1]), a1);
            a2 = pkfma(rv, f2(((const float*)&wf[2][0])[d], ((const float*)&wf[2][0])[d + 1]), a2);
            a3 = pkfma(rv, f2(((const float*)&wf[3][0])[d], ((const float*)&wf[3][0])[d + 1]), a3);
        }
        const float rl = rr[11];
        float4 ov;
        ov.x = (a0.x + a0.y + rr[10] * wf[0][2].z) * rl + bv.x;
        ov.y = (a1.x + a1.y + rr[10] * wf[1][2].z) * rl + bv.y;
        ov.z = (a2.x + a2.y + rr[10] * wf[2][2].z) * rl + bv.z;
        ov.w = (a3.x + a3.y + rr[10] * wf[3][2].z) * rl + bv.w;
        *(float4*)(out + (size_t)(t0 + r) * E_DIM + e0) = ov;
    }
}

// ---------------------------------------------------------------------------
extern "C" void kernel_launch(void* const* d_in, const int* in_sizes, int n_in,
                              void* d_out, int out_size, void* d_ws, size_t ws_size,
                              hipStream_t stream) {
    const float* xe = (const float*)d_in[1];
    const float* Wk = (const float*)d_in[2];
    const float* bk = (const float*)d_in[3];
    const float* Wq = (const float*)d_in[4];
    const float* bq = (const float*)d_in[5];
    const float* Wv = (const float*)d_in[6];
    const float* bv = (const float*)d_in[7];
    const float* Wf = (const float*)d_in[8];
    const float* bf = (const float*)d_in[9];
    float* out = (float*)d_out;

    float* qkvF  = (float*)d_ws;                              // [T][QS]
    float* wfp   = qkvF + (size_t)T_SEQ * QS;                 // [E][12]
    float* partQ = wfp + (size_t)E_DIM * 12;                  // [QNEC][T][QS]
    float* part  = partQ;                                     // overlay: [64][T][12]

    prep_wf<<<(E_DIM * 12 + 255) / 256, 256, 0, stream>>>(Wf, wfp);
    qkv_proj<<<dim3(T_SEQ / QRB, QNEC), 256, 0, stream>>>(xe, Wk, bk, Wq, bq, Wv, bv, partQ);
    reduceQ<<<(T_SEQ * (QS / 4)) / 256, 256, 0, stream>>>(partQ, qkvF);
    const int nrb = T_SEQ / ARB;                              // 64
    attn<<<nrb * (nrb + 1) / 2, 64, 0, stream>>>(qkvF, part); // 2080 blocks
    pass2<<<T_SEQ / TR, 256, 0, stream>>>(part, wfp, bf, out);
}